// Round 9
// baseline (2830.248 us; speedup 1.0000x reference)
//
#include <hip/hip_runtime.h>
#include <math.h>

#define HID 512
#define TENC 16384
#define NBLK 256
#define TPB 512
#define KPB 64
#define GRPSZ 8
#define VOCAB 31
#define EOSI 29
#define MAXLEN 100
#define SCALE 0.044194173824159216f

// ws layout (4-byte units)
#define WS_GX    0          // 31*1536 = 47616
#define WS_GH    47616      // 2*1536 (double buffer)
#define WS_LT    50688      // 3 buffers * 272  (8 slots*32 lognum, +256: 8 T1)
#define WS_BAR   51504      // ints: 100*128 counters = 12800

#define OUT_LEN_IDX 3100
#define OUT_ATT_BASE 3101

#define AL(p)    __hip_atomic_load((p), __ATOMIC_RELAXED, __HIP_MEMORY_SCOPE_AGENT)
#define AS(p, v) __hip_atomic_store((p), (v), __ATOMIC_RELAXED, __HIP_MEMORY_SCOPE_AGENT)

static __device__ __forceinline__ float wsum(float v) {
#pragma unroll
  for (int m = 32; m >= 1; m >>= 1) v += __shfl_xor(v, m, 64);
  return v;
}
static __device__ __forceinline__ float sigm(float x) { return 1.0f / (1.0f + __expf(-x)); }
static __device__ __forceinline__ float ftanh(float x) {
  return 1.0f - 2.0f / (__expf(2.0f * x) + 1.0f);
}

__global__ __launch_bounds__(1024) void k_init(const float* __restrict__ b_hh,
                                               float* __restrict__ ws) {
  int idx = blockIdx.x * 1024 + threadIdx.x;
  int* bars = (int*)ws + WS_BAR;
  if (idx < 12800) bars[idx] = 0;
  if (idx < 1536) ws[WS_GH + idx] = b_hh[idx];  // gh(0) = W_hh*0 + b_hh (buffer 0)
  if (idx < 816) ws[WS_LT + idx] = 0.0f;        // all 3 LT buffers
}

__global__ __launch_bounds__(256) void k_gx_all(const float* __restrict__ embed,
                                                const float* __restrict__ w_ih,
                                                const float* __restrict__ b_ih,
                                                float* __restrict__ ws) {
  int w = threadIdx.x >> 6, lane = threadIdx.x & 63;
  int r = blockIdx.x * 4 + w;
  float wr[8];
  const float* wp = w_ih + (size_t)r * HID + lane * 8;
#pragma unroll
  for (int j = 0; j < 8; ++j) wr[j] = wp[j];
  float b = b_ih[r];
  for (int v = 0; v < VOCAB; ++v) {
    const float* e = embed + (size_t)v * HID + lane * 8;
    float d = 0.f;
#pragma unroll
    for (int j = 0; j < 8; ++j) d += wr[j] * e[j];
    d = wsum(d);
    if (lane == 0) ws[WS_GX + v * 1536 + r] = d + b;
  }
}

// fence-free grid barrier, flat detect: every block's wave0 scans the 32
// arrival counters directly (no epoch publish hop). All cross-block data is
// device-scope atomic, so no cache invalidation is ever needed.
static __device__ __forceinline__ void gridbar(int* bars, int t) {
  __syncthreads();
  int* cbase = bars + t * 128;
  if (threadIdx.x == 0)
    __hip_atomic_fetch_add(cbase + (blockIdx.x & 31) * 4, 1,
                           __ATOMIC_RELEASE, __HIP_MEMORY_SCOPE_AGENT);
  if (threadIdx.x < 64) {
    for (;;) {
      int c = AL(cbase + (threadIdx.x & 31) * 4);
      if (__all(c >= GRPSZ)) break;
      __builtin_amdgcn_s_sleep(2);
    }
  }
  __syncthreads();
}

__global__ __launch_bounds__(TPB, 1) void k_persist(const float* __restrict__ enc,
                                                    const float* __restrict__ w_hh,
                                                    const float* __restrict__ b_hh,
                                                    const float* __restrict__ w_out,
                                                    const float* __restrict__ b_out,
                                                    float* __restrict__ ws,
                                                    float* __restrict__ dout) {
  const int tid = threadIdx.x, blk = blockIdx.x;
  const int w = tid >> 6, lane = tid & 63;
  __shared__ __align__(16) float k_lds[KPB][HID];   // 128 KiB
  __shared__ __align__(16) float uwave[8][HID];     // 16 KiB per-wave PV partials
  __shared__ __align__(16) float h2[2][HID];
  __shared__ __align__(16) float uld[HID];
  __shared__ float sblk[KPB];
  __shared__ float okf[KPB];
  __shared__ float pb_lds[32];
  __shared__ float lgs[34];
  __shared__ float ered[8];
  int best = EOSI, len = MAXLEN;
  int* bars = (int*)ws + WS_BAR;

  // ---- stage K into LDS (lane*4 / 256+lane*4, bank-perfect), V into REGISTERS ----
  float4 v0[8], v1[8];
#pragma unroll
  for (int rr = 0; rr < 8; ++rr) {
    int r = w * 8 + rr;
    const float* rp = enc + (size_t)(blk * KPB + r) * 1024;
    float4 k0 = *(const float4*)(rp + lane * 4);
    float4 k1 = *(const float4*)(rp + 256 + lane * 4);
    v0[rr] = *(const float4*)(rp + 512 + lane * 4);
    v1[rr] = *(const float4*)(rp + 768 + lane * 4);
    *(float4*)&k_lds[r][lane * 4] = k0;
    *(float4*)&k_lds[r][256 + lane * 4] = k1;
    bool okl = (k0.x != 30.f) || (k0.y != 30.f) || (k0.z != 30.f) || (k0.w != 30.f)
             || (k1.x != 30.f) || (k1.y != 30.f) || (k1.z != 30.f) || (k1.w != 30.f);
    bool ok = (__ballot(okl) != 0ull);
    if (lane == 0) okf[r] = ok ? 1.0f : 0.0f;
  }
  if (tid < HID) h2[0][tid] = 0.f;
  __syncthreads();

#pragma unroll 1
  for (int t = 0;; ++t) {
    float* h = h2[t & 1];
    float* hn = h2[(t + 1) & 1];

    // ---- issue gh(t) loads FIRST (independent of argmax; overlaps LT round trip) ----
    const float* ghb = ws + WS_GH + (t & 1) * 1536;
    float ghr = AL(ghb + tid);
    float ghz = AL(ghb + HID + tid);
    float ghn = AL(ghb + 2 * HID + tid);

    // ================= phase A: finalize step t-1 =================
    if (t > 0) {
      const float* LT = ws + WS_LT + ((t - 1) % 3) * 272;
      if (tid < 64) {
        float val = 0.f;
        if (lane < VOCAB) {
#pragma unroll
          for (int s = 0; s < 8; ++s) val += AL(LT + s * 32 + lane);
        } else if (lane == 32) {
#pragma unroll
          for (int s = 0; s < 8; ++s) val += AL(LT + 256 + s);
        }
        float t1 = __shfl(val, 32, 64);
        if (lane < VOCAB) lgs[lane] = val / t1 + pb_lds[lane];
        if (lane == 32) lgs[32] = t1;
      }
      __syncthreads();
      float bv = lgs[0];
      int bb = 0;
#pragma unroll
      for (int v = 1; v < VOCAB; ++v) {
        float x = lgs[v];
        if (x > bv) { bv = x; bb = v; }
      }
      best = bb;
      if (bb == EOSI && len == MAXLEN) len = t - 1;
      float invT1 = 1.0f / lgs[32];
      if (tid < KPB)
        dout[OUT_ATT_BASE + (size_t)(t - 1) * TENC + blk * KPB + tid] = sblk[tid] * invT1;
      if (blk == 17) {
        if (tid < VOCAB) dout[(size_t)(t - 1) * VOCAB + tid] = lgs[tid];
        if (t == MAXLEN && tid == 0) dout[OUT_LEN_IDX] = (float)len;
      }
      if (blk == 9) {
        float* LTn = ws + WS_LT + ((t + 1) % 3) * 272;
        if (tid < 264) AS(LTn + tid, 0.0f);  // zero buffer for step t+1
      }
    }
    if (t == MAXLEN) break;

    // ================= phase B =================
    // B1: GRU (redundant per block, bitwise identical; gh already in regs)
    {
      const float* gx = ws + WS_GX + best * 1536;
      float gxr = gx[tid], gxz = gx[HID + tid], gxn = gx[2 * HID + tid];
      float rg = sigm(gxr + ghr);
      float zg = sigm(gxz + ghz);
      float ng = ftanh(gxn + rg * ghn);
      hn[tid] = (1.f - zg) * ng + zg * h[tid];
    }
    __syncthreads();

    // B2: gh(t+1) slice, rows blk*6 .. +5 (global w_hh, L2-hot, x LDS hn)
    if (w < 6) {
      int r = blk * 6 + w;
      const float* wp = w_hh + (size_t)r * HID;
      float4 w0 = *(const float4*)(wp + lane * 4);
      float4 w1 = *(const float4*)(wp + 256 + lane * 4);
      float4 hv0 = *(const float4*)(&hn[lane * 4]);
      float4 hv1 = *(const float4*)(&hn[256 + lane * 4]);
      float acc = w0.x*hv0.x + w0.y*hv0.y + w0.z*hv0.z + w0.w*hv0.w
                + w1.x*hv1.x + w1.y*hv1.y + w1.z*hv1.z + w1.w*hv1.w;
      acc = wsum(acc);
      if (lane == 0) AS(ws + WS_GH + ((t + 1) & 1) * 1536 + r, acc + b_hh[r]);
    }

    // B3: scores from LDS K (bank-perfect), V from registers
    float4 hv0 = *(const float4*)(&hn[lane * 4]);
    float4 hv1 = *(const float4*)(&hn[256 + lane * 4]);
    float ee[8];
    float esum = 0.f;
#pragma unroll
    for (int rr = 0; rr < 8; ++rr) {
      int r = w * 8 + rr;
      float4 k0 = *(const float4*)(&k_lds[r][lane * 4]);
      float4 k1 = *(const float4*)(&k_lds[r][256 + lane * 4]);
      float d = hv0.x*k0.x + hv0.y*k0.y + hv0.z*k0.z + hv0.w*k0.w
              + hv1.x*k1.x + hv1.y*k1.y + hv1.z*k1.z + hv1.w*k1.w;
      float s = wsum(d);
      float e = okf[r] * __expf(s * SCALE);  // no-max softmax: |s*SCALE| <= ~23
      ee[rr] = e;
      if (lane == 0) sblk[r] = e;
      esum += e;
    }
    if (lane == 0) ered[w] = esum;
    {
      float p0 = 0.f, p1 = 0.f, p2 = 0.f, p3 = 0.f;
      float p4 = 0.f, p5 = 0.f, p6 = 0.f, p7 = 0.f;
#pragma unroll
      for (int rr = 0; rr < 8; ++rr) {
        float e = ee[rr];
        p0 += e * v0[rr].x; p1 += e * v0[rr].y; p2 += e * v0[rr].z; p3 += e * v0[rr].w;
        p4 += e * v1[rr].x; p5 += e * v1[rr].y; p6 += e * v1[rr].z; p7 += e * v1[rr].w;
      }
      *(float4*)&uwave[w][lane * 4] = make_float4(p0, p1, p2, p3);
      *(float4*)&uwave[w][256 + lane * 4] = make_float4(p4, p5, p6, p7);
    }
    __syncthreads();
    // cross-wave reduce of PV partials (stride-512 reads, conflict-free)
    uld[tid] = uwave[0][tid] + uwave[1][tid] + uwave[2][tid] + uwave[3][tid]
             + uwave[4][tid] + uwave[5][tid] + uwave[6][tid] + uwave[7][tid];
    if (tid == 0) {
      float T1p = ered[0] + ered[1] + ered[2] + ered[3]
                + ered[4] + ered[5] + ered[6] + ered[7];
      atomicAdd(ws + WS_LT + (t % 3) * 272 + 256 + (blk & 7), T1p);
    }
    __syncthreads();

    // B5: logit partials. accs = w_out_s . u_blk (atomic-summed); acch redundant
    for (int r = w; r < VOCAB; r += 8) {
      const float* wo = w_out + (size_t)r * 1024;
      float4 a0 = *(const float4*)(wo + lane * 4);
      float4 a1 = *(const float4*)(wo + 256 + lane * 4);
      float4 b0 = *(const float4*)(wo + 512 + lane * 4);
      float4 b1 = *(const float4*)(wo + 768 + lane * 4);
      float4 u0 = *(const float4*)(&uld[lane * 4]);
      float4 u1 = *(const float4*)(&uld[256 + lane * 4]);
      float4 q0 = *(const float4*)(&hn[lane * 4]);
      float4 q1 = *(const float4*)(&hn[256 + lane * 4]);
      float accs = a0.x*u0.x + a0.y*u0.y + a0.z*u0.z + a0.w*u0.w
                 + a1.x*u1.x + a1.y*u1.y + a1.z*u1.z + a1.w*u1.w;
      float acch = b0.x*q0.x + b0.y*q0.y + b0.z*q0.z + b0.w*q0.w
                 + b1.x*q1.x + b1.y*q1.y + b1.z*q1.z + b1.w*q1.w;
      accs = wsum(accs);
      acch = wsum(acch);
      if (lane == 0) {
        atomicAdd(ws + WS_LT + (t % 3) * 272 + (blk & 7) * 32 + r, accs);
        pb_lds[r] = acch + b_out[r];
      }
    }

    gridbar(bars, t);
  }
}

extern "C" void kernel_launch(void* const* d_in, const int* in_sizes, int n_in,
                              void* d_out, int out_size, void* d_ws, size_t ws_size,
                              hipStream_t stream) {
  const float* enc   = (const float*)d_in[0];
  const float* embed = (const float*)d_in[2];
  const float* w_ih  = (const float*)d_in[3];
  const float* w_hh  = (const float*)d_in[4];
  const float* b_ih  = (const float*)d_in[5];
  const float* b_hh  = (const float*)d_in[6];
  const float* w_out = (const float*)d_in[7];
  const float* b_out = (const float*)d_in[8];
  float* dout = (float*)d_out;
  float* ws = (float*)d_ws;

  hipLaunchKernelGGL(k_init, dim3(13), dim3(1024), 0, stream, b_hh, ws);
  hipLaunchKernelGGL(k_gx_all, dim3(384), dim3(256), 0, stream, embed, w_ih, b_ih, ws);
  hipLaunchKernelGGL(k_persist, dim3(NBLK), dim3(TPB), 0, stream,
                     enc, w_hh, b_hh, w_out, b_out, ws, dout);
}